// Round 1
// baseline (167.592 us; speedup 1.0000x reference)
//
#include <hip/hip_runtime.h>
#include <hip/hip_bf16.h>
#include <math.h>

// Problem constants (from reference): N=1e6 points, M=1e5 segments, D=64, K=32.
// pt_inv is SORTED -> segments are contiguous point ranges -> no atomics needed.

#define D_IN 64
#define K_OUT 32
#define WAVES_PER_BLOCK 4

// Kernel 1: starts[s] = first p with pt_inv[p] >= s, for s in [0, M] (M+1 entries).
__global__ __launch_bounds__(256) void seg_starts_kernel(
    const int* __restrict__ pt_inv, int n, int* __restrict__ starts, int M)
{
    int s = blockIdx.x * blockDim.x + threadIdx.x;
    if (s > M) return;
    int lo = 0, hi = n;
    while (lo < hi) {
        int mid = (lo + hi) >> 1;
        if (pt_inv[mid] < s) lo = mid + 1; else hi = mid;
    }
    starts[s] = lo;
}

// Kernel 2: fused gather+add -> segment max -> (pooled @ W + b) -> relu -> out.
// One 64-lane wave per segment; lane = feature column.
__global__ __launch_bounds__(64 * WAVES_PER_BLOCK) void pool_gemm_kernel(
    const int*   __restrict__ shuffled_ind,
    const float* __restrict__ g,      // [N, 64]
    const float* __restrict__ l,      // [N, 64]
    const int*   __restrict__ starts, // [M+1]
    const float* __restrict__ W,      // [64, 32]
    const float* __restrict__ b,      // [32]
    float*       __restrict__ out,    // [M, 32]
    int M)
{
    __shared__ float Ws[D_IN * K_OUT];   // 8 KiB
    __shared__ float bs[K_OUT];
    __shared__ float pool[WAVES_PER_BLOCK][D_IN];

    const int tid = threadIdx.x;
    for (int i = tid; i < D_IN * K_OUT; i += 64 * WAVES_PER_BLOCK) Ws[i] = W[i];
    if (tid < K_OUT) bs[tid] = b[tid];

    const int wid  = tid >> 6;
    const int lane = tid & 63;
    const int s    = blockIdx.x * WAVES_PER_BLOCK + wid;
    const bool active = (s < M);

    float m = -INFINITY;
    if (active) {
        const int p0 = starts[s];
        const int p1 = starts[s + 1];
        for (int p = p0; p < p1; ++p) {
            const int ind = shuffled_ind[p];
            const float x = g[(size_t)ind * D_IN + lane] + l[(size_t)p * D_IN + lane];
            m = fmaxf(m, x);
        }
        if (p1 <= p0) m = 0.0f;   // empty segment -> 0 (matches isfinite fixup)
    }

    if (active) pool[wid][lane] = m;
    __syncthreads();   // covers both Ws/bs preload and pool[] visibility

    if (active && lane < K_OUT) {
        float acc = bs[lane];
        #pragma unroll
        for (int c = 0; c < D_IN; ++c) {
            acc = fmaf(pool[wid][c], Ws[c * K_OUT + lane], acc);
        }
        out[(size_t)s * K_OUT + lane] = fmaxf(acc, 0.0f);
    }
}

extern "C" void kernel_launch(void* const* d_in, const int* in_sizes, int n_in,
                              void* d_out, int out_size, void* d_ws, size_t ws_size,
                              hipStream_t stream)
{
    const int*   shuffled_ind = (const int*)  d_in[0];
    const float* g            = (const float*)d_in[1];
    const float* l            = (const float*)d_in[2];
    const int*   pt_inv       = (const int*)  d_in[3];
    const float* W            = (const float*)d_in[4];
    const float* b            = (const float*)d_in[5];
    float*       out          = (float*)d_out;

    const int N = in_sizes[0];          // 1,000,000
    const int M = out_size / K_OUT;     // 100,000

    int* starts = (int*)d_ws;           // (M+1) ints

    {
        int threads = 256;
        int blocks  = (M + 1 + threads - 1) / threads;
        seg_starts_kernel<<<blocks, threads, 0, stream>>>(pt_inv, N, starts, M);
    }
    {
        int blocks = (M + WAVES_PER_BLOCK - 1) / WAVES_PER_BLOCK;
        pool_gemm_kernel<<<blocks, 64 * WAVES_PER_BLOCK, 0, stream>>>(
            shuffled_ind, g, l, starts, W, b, out, M);
    }
}